// Round 22
// baseline (166.485 us; speedup 1.0000x reference)
//
#include <hip/hip_runtime.h>
#include <hip/hip_bf16.h>
#include <stdint.h>

#define EPS 1e-5f
#define SLOPE 0.2f

typedef __attribute__((ext_vector_type(8))) short short8;
typedef __attribute__((ext_vector_type(4))) float f32x4;

static __device__ inline ushort f2bf(float f) {
  __hip_bfloat16 h = __float2bfloat16(f);
  return *reinterpret_cast<ushort*>(&h);
}

static __device__ inline short8 u4_to_s8(uint a, uint b, uint c, uint d) {
  union { uint4 u; short8 s; } cv;
  cv.u.x = a; cv.u.y = b; cv.u.z = c; cv.u.w = d;
  return cv.s;
}

// ---------------------------------------------------------------------------
// Fused: zero XCLP halo (blocks [0,1124)) + mask dtype detection (rest).
// ---------------------------------------------------------------------------
__global__ void zdetect_k(uint4* __restrict__ zp, int n16,
                          const uint8_t* __restrict__ raw, int nbytes,
                          unsigned* __restrict__ flag) {
  int bid = blockIdx.x;
  if (bid < 1124) {
    int i = bid * 256 + threadIdx.x;
    if (i < n16) zp[i] = make_uint4(0u, 0u, 0u, 0u);
    return;
  }
  unsigned local = 0;
  for (int i = (bid - 1124) * 256 + threadIdx.x; i < nbytes; i += 256 * 256)
    if (i & 3) local |= raw[i];
  if (local) atomicOr(flag, 1u);
}

// Fused mask-convert + input pack into PADDED [2][66][66][66][4] bf16.
__global__ void xclm_k(const float* __restrict__ x, const uint8_t* __restrict__ raw,
                       const unsigned* __restrict__ flag,
                       uint8_t* __restrict__ m1, ushort* __restrict__ xclp) {
  int id = blockIdx.x * blockDim.x + threadIdx.x;
  if (id >= 2 * 262144) return;
  uint8_t v;
  if (*flag) {
    v = raw[id];
  } else {
    size_t j = 4 * (size_t)id;
    v = (uint8_t)(raw[j] | raw[j + 1] | raw[j + 2] | raw[j + 3]);
  }
  v = v ? 1 : 0;
  m1[id] = v;
  float mk = (float)v;
  int b  = id >> 18;
  int sp = id & 262143;
  int xx = sp & 63, yy = (sp >> 6) & 63, zz = sp >> 12;
  size_t base = (size_t)b * 3 * 262144 + sp;
  float x0 = x[base] * mk;
  float x1 = x[base + 262144] * mk;
  float x2 = x[base + 2 * 262144] * mk;
  uint2 u;
  u.x = ((uint)f2bf(x1) << 16) | (uint)f2bf(x0);
  u.y = (uint)f2bf(x2);
  size_t pidx = ((((size_t)(b * 66 + zz + 1)) * 66 + (yy + 1)) * 66 + (xx + 1)) * 4;
  *reinterpret_cast<uint2*>(xclp + pidx) = u;
}

// ---------------------------------------------------------------------------
// Fused prep v2: LDS-tiled per-row weight transposes + wb1 + mask pyramid.
// ---------------------------------------------------------------------------
__global__ __launch_bounds__(256) void prep2_k(
    const float* __restrict__ w1, const float* __restrict__ w2,
    const float* __restrict__ w3, const float* __restrict__ w4,
    ushort* __restrict__ wb1, ushort* __restrict__ wb2,
    ushort* __restrict__ wb3, ushort* __restrict__ wb4,
    const uint8_t* __restrict__ m1, uint8_t* __restrict__ m2,
    uint8_t* __restrict__ m3, uint8_t* __restrict__ m4) {
  __shared__ ushort ls[6912];
  const int t   = threadIdx.x;
  const int bid = blockIdx.x;

  if (bid < 896) {
    const float* w; ushort* wb; int c, K, l2c;
    if (bid < 512)      { w = w4; wb = wb4; c = bid;       K = 6912; l2c = 8; }
    else if (bid < 768) { w = w3; wb = wb3; c = bid - 512; K = 3456; l2c = 7; }
    else                { w = w2; wb = wb2; c = bid - 768; K = 1728; l2c = 6; }
    const float* src = w + (size_t)c * K;
    for (int i = t; i < K; i += 256) ls[i] = f2bf(src[i]);
    __syncthreads();
    ushort* dst = wb + (size_t)c * K;
    const int cm = (1 << l2c) - 1;
    for (int kn = t; kn < K; kn += 256) {
      int off = kn >> l2c, ci = kn & cm;
      dst[kn] = ls[ci * 27 + off];
    }
    return;
  }
  if (bid == 896) {
    for (int id = t; id < 8192; id += 256) {
      int k = id & 127, c = id >> 7;
      int tap = k >> 2, ci = k & 3;
      float v = (tap < 27 && ci < 3) ? w1[c * 81 + ci * 27 + tap] : 0.f;
      wb1[id] = f2bf(v);
    }
    return;
  }
  int id = (bid - 897) * 256 + t;
  if (id >= 74752) return;
  int Wl, rad, sh;
  uint8_t* mo;
  if (id < 65536)      { Wl = 32; rad = 1; sh = 1; mo = m2; }
  else if (id < 73728) { id -= 65536; Wl = 16; rad = 3; sh = 2; mo = m3; }
  else                 { id -= 73728; Wl = 8;  rad = 7; sh = 3; mo = m4; }
  int xo = id % Wl; int tt = id / Wl;
  int yo = tt % Wl; tt /= Wl;
  int zo = tt % Wl; int b = tt / Wl;
  int cx = xo << sh, cy = yo << sh, cz = zo << sh;
  int zlo = max(cz - rad, 0), zhi = min(cz + rad, 63);
  int ylo = max(cy - rad, 0), yhi = min(cy + rad, 63);
  int xlo = max(cx - rad, 0), xhi = min(cx + rad, 63);
  int any = 0;
  for (int z = zlo; z <= zhi && !any; ++z)
    for (int y = ylo; y <= yhi && !any; ++y)
      for (int x = xlo; x <= xhi; ++x)
        any |= m1[(((size_t)b * 64 + z) * 64 + y) * 64 + x];
  mo[(((size_t)b * Wl + zo) * Wl + yo) * Wl + xo] = any ? 1 : 0;
}

// ---------------------------------------------------------------------------
// Block1 GEMM via LDS spatial tile: 512 threads (8 waves), 8 z-slices per
// block, wb1 staged once into LDS. NEW: LN epilogue uses mask-folded FMA
// coefficients (leaky(m*a)=m*leaky(a) for m in {0,1}) — 3 VALU/elem.
// ---------------------------------------------------------------------------
__global__ __launch_bounds__(512) void conv1_gemm(
    const ushort* __restrict__ xclp,    // [2][66][66][66][4] bf16, zero halo
    const ushort* __restrict__ wb1,     // [64][128] bf16
    const float* __restrict__ gamma,
    const float* __restrict__ beta,
    const uint8_t* __restrict__ msk,    // [2*64^3]
    ushort* __restrict__ out)           // [2*64^3][64] bf16
{
  const int t    = threadIdx.x;
  const int lane = t & 63;
  const int wave = t >> 6;
  const int wv   = wave & 3;
  const int grp  = wave >> 2;
  const int c8   = lane >> 4;

  const int bid = blockIdx.x;           // 512 = 2*8*32
  const int yp = bid & 31;
  const int zo = (bid >> 5) & 7;
  const int b  = bid >> 8;
  const int y0 = yp * 2;
  const int z0 = zo * 8;

  __shared__ uint2 tile[2640];          // [p 0..9][r 0..3][x 0..65]
  __shared__ ushort wlds[64 * 136];     // wb1 rows padded to 136

  const uint2* xin = reinterpret_cast<const uint2*>(xclp);
  const long gbase = (((long)(b * 66 + z0)) * 66 + y0) * 66;
  for (int e = t; e < 2640; e += 512) {
    int p = e / 264;
    tile[e] = xin[gbase + e + p * 4092];
  }
  for (int e = t; e < 8192; e += 512) {
    int row = e >> 7, k = e & 127;
    wlds[row * 136 + k] = wb1[e];
  }

  int eoff[2][2][2];
#pragma unroll
  for (int kb = 0; kb < 2; ++kb)
#pragma unroll
    for (int kh = 0; kh < 2; ++kh)
#pragma unroll
      for (int p = 0; p < 2; ++p) {
        int tap = kb * 16 + kh * 8 + c8 * 2 + p;
        int off = 0;
        if (tap < 27) {
          int dz = tap / 9, rr = tap - dz * 9;
          int dy = rr / 3, dx = rr - dy * 3;
          off = dz * 264 + dy * 66 + dx;
        }
        eoff[kb][kh][p] = off;
      }

  int ebase[2];
#pragma unroll
  for (int nf = 0; nf < 2; ++nf) {
    int nl = wv * 32 + nf * 16 + (lane & 15);
    ebase[nf] = (nl >> 6) * 66 + (nl & 63);
  }

  float gr[4][4], br_[4][4];
#pragma unroll
  for (int mf = 0; mf < 4; ++mf) {
    int cb = mf * 16 + c8 * 4;
    f32x4 gv  = *reinterpret_cast<const f32x4*>(gamma + cb);
    f32x4 bv2 = *reinterpret_cast<const f32x4*>(beta + cb);
#pragma unroll
    for (int r = 0; r < 4; ++r) { gr[mf][r] = gv[r]; br_[mf][r] = bv2[r]; }
  }

  __syncthreads();

  for (int zz = 0; zz < 4; ++zz) {
    const int zi  = 2 * zz + grp;
    const int zsh = zi * 264;
    f32x4 acc[4][2];
#pragma unroll
    for (int i = 0; i < 4; ++i)
#pragma unroll
      for (int j = 0; j < 2; ++j) acc[i][j] = (f32x4)(0.f);

#pragma unroll
    for (int kb = 0; kb < 2; ++kb) {
      short8 afr[4][2];
#pragma unroll
      for (int mf = 0; mf < 4; ++mf)
#pragma unroll
        for (int kh = 0; kh < 2; ++kh) {
          int row = mf * 16 + (lane & 15);
          int k   = kb * 64 + (c8 + kh * 4) * 8;
          afr[mf][kh] = *reinterpret_cast<const short8*>(&wlds[row * 136 + k]);
        }
#pragma unroll
      for (int nf = 0; nf < 2; ++nf)
#pragma unroll
        for (int kh = 0; kh < 2; ++kh) {
          uint2 v0 = tile[ebase[nf] + zsh + eoff[kb][kh][0]];
          uint2 v1 = tile[ebase[nf] + zsh + eoff[kb][kh][1]];
          short8 bfr = u4_to_s8(v0.x, v0.y, v1.x, v1.y);
#pragma unroll
          for (int mf = 0; mf < 4; ++mf)
            acc[mf][nf] = __builtin_amdgcn_mfma_f32_16x16x32_bf16(
                afr[mf][kh], bfr, acc[mf][nf], 0, 0, 0);
        }
    }

    const int z = z0 + zi;
    const int voxbase = ((b * 64 + z) * 64 + y0) * 64;
#pragma unroll
    for (int nf = 0; nf < 2; ++nf) {
      float s = 0.f, sq = 0.f;
#pragma unroll
      for (int mf = 0; mf < 4; ++mf)
#pragma unroll
        for (int r = 0; r < 4; ++r) {
          float v = acc[mf][nf][r];
          s += v; sq += v * v;
        }
      s  += __shfl_xor(s, 16);  sq += __shfl_xor(sq, 16);
      s  += __shfl_xor(s, 32);  sq += __shfl_xor(sq, 32);
      const float mean = s * (1.f / 64.f);
      const float var  = sq * (1.f / 64.f) - mean * mean;
      const float rstd = rsqrtf(var + EPS);
      const int vox = voxbase + wv * 32 + nf * 16 + (lane & 15);
      const float mk = msk[vox] ? 1.f : 0.f;
      const float mr = mk * rstd;          // fold mask into coefficients
#pragma unroll
      for (int mf = 0; mf < 4; ++mf) {
        uint2 u;
        float cg0 = mr * gr[mf][0], cg1 = mr * gr[mf][1];
        float cg2 = mr * gr[mf][2], cg3 = mr * gr[mf][3];
        float cb0 = fmaf(-mean, cg0, mk * br_[mf][0]);
        float cb1 = fmaf(-mean, cg1, mk * br_[mf][1]);
        float cb2 = fmaf(-mean, cg2, mk * br_[mf][2]);
        float cb3 = fmaf(-mean, cg3, mk * br_[mf][3]);
        float r0 = fmaf(acc[mf][nf][0], cg0, cb0);
        float r1 = fmaf(acc[mf][nf][1], cg1, cb1);
        float r2 = fmaf(acc[mf][nf][2], cg2, cb2);
        float r3 = fmaf(acc[mf][nf][3], cg3, cb3);
        r0 = r0 > 0.f ? r0 : SLOPE * r0;
        r1 = r1 > 0.f ? r1 : SLOPE * r1;
        r2 = r2 > 0.f ? r2 : SLOPE * r2;
        r3 = r3 > 0.f ? r3 : SLOPE * r3;
        u.x = ((uint)f2bf(r1) << 16) | (uint)f2bf(r0);
        u.y = ((uint)f2bf(r3) << 16) | (uint)f2bf(r2);
        *reinterpret_cast<uint2*>(out + (size_t)vox * 64 + mf * 16 + c8 * 4) = u;
      }
    }
  }
}

// ---------------------------------------------------------------------------
// Block2: LDS double-buffered implicit GEMM 64->128 s2, FUSED LN epilogue.
// (R9-proven BN=128: A+B both LDS-staged.)
// ---------------------------------------------------------------------------
__global__ __launch_bounds__(256) void conv2_gemm(
    const ushort* __restrict__ in,      // t1 [524288][64] bf16
    const ushort* __restrict__ wbf,     // wb2 [128][1728] bf16
    const float* __restrict__ gamma,
    const float* __restrict__ beta,
    const uint8_t* __restrict__ msk,    // m2 [65536]
    ushort* __restrict__ out,           // t2 [65536][128] bf16
    const ushort* __restrict__ zpage)
{
  constexpr int CIN = 64, DIN = 64, S = 2;
  constexpr int W = 32, K = 1728, NT = 27, LW = 5;

  const int t    = threadIdx.x;
  const int lane = t & 63;
  const int wave = t >> 6;
  int bid = blockIdx.x;
  bid = (bid & 7) * 64 + (bid >> 3);        // XCD swizzle (512 = 8*64)
  const int n0 = bid * 128;

  __shared__ short As[2][128 * 64];
  __shared__ short Bs[2][128 * 64];
  __shared__ float lnS[4][4][16];
  __shared__ float lnQ[4][4][16];

  int zb[4], yb[4], xb[4], kc8[4], swz[4];
  size_t bb[4];
  const ushort* aptr[4];
#pragma unroll
  for (int j = 0; j < 4; ++j) {
    int q  = t + 256 * j;
    int nl = q >> 3, kc = q & 7;
    kc8[j] = kc * 8;
    swz[j] = nl * 64 + ((kc ^ (nl & 7)) << 3);
    int ngv = n0 + nl;
    int xo = ngv & (W - 1), yo = (ngv >> LW) & (W - 1),
        zo = (ngv >> (2 * LW)) & (W - 1), b = ngv >> (3 * LW);
    xb[j] = xo * S; yb[j] = yo * S; zb[j] = zo * S;
    bb[j] = (size_t)b * CIN * DIN * DIN * DIN;
    aptr[j] = wbf + (size_t)nl * K + kc * 8;
  }

  short8 ar[4], br[4];

  auto LOADK = [&](int kb) {
    const int off = kb;                      // 64 k = 1 tap (CIN=64)
    const int dz = off / 9, rr = off % 9;
    const int dy = rr / 3, dx = rr % 3;
#pragma unroll
    for (int j = 0; j < 4; ++j) {
      ar[j] = *reinterpret_cast<const short8*>(aptr[j] + kb * 64);
      int zin = zb[j] + dz - 1;
      int yin = yb[j] + dy - 1;
      int xin = xb[j] + dx - 1;
      bool ok = ((unsigned)zin < (unsigned)DIN) &&
                ((unsigned)yin < (unsigned)DIN) &&
                ((unsigned)xin < (unsigned)DIN);
      const ushort* p = ok
          ? in + bb[j] + (((size_t)zin * DIN + yin) * DIN + xin) * CIN + kc8[j]
          : zpage;
      br[j] = *reinterpret_cast<const short8*>(p);
    }
  };

  auto WRITEK = [&](int buf) {
#pragma unroll
    for (int j = 0; j < 4; ++j) {
      *reinterpret_cast<short8*>(&As[buf][swz[j]]) = ar[j];
      *reinterpret_cast<short8*>(&Bs[buf][swz[j]]) = br[j];
    }
  };

  f32x4 acc[4][4];
#pragma unroll
  for (int i = 0; i < 4; ++i)
#pragma unroll
    for (int j = 0; j < 4; ++j) acc[i][j] = (f32x4)(0.f);

  const int wm = (wave & 1) * 64;
  const int wn = (wave >> 1) * 64;

  LOADK(0);
  for (int kb = 0; kb < NT; ++kb) {
    const int buf = kb & 1;
    WRITEK(buf);
    if (kb + 1 < NT) LOADK(kb + 1);
    __syncthreads();

    short8 afr[4][2], bfr[4][2];
#pragma unroll
    for (int mf = 0; mf < 4; ++mf)
#pragma unroll
      for (int kh = 0; kh < 2; ++kh) {
        int row  = wm + mf * 16 + (lane & 15);
        int slot = (lane >> 4) + kh * 4;
        afr[mf][kh] = *reinterpret_cast<const short8*>(
            &As[buf][row * 64 + ((slot ^ (row & 7)) << 3)]);
      }
#pragma unroll
    for (int nf = 0; nf < 4; ++nf)
#pragma unroll
      for (int kh = 0; kh < 2; ++kh) {
        int row  = wn + nf * 16 + (lane & 15);
        int slot = (lane >> 4) + kh * 4;
        bfr[nf][kh] = *reinterpret_cast<const short8*>(
            &Bs[buf][row * 64 + ((slot ^ (row & 7)) << 3)]);
      }
#pragma unroll
    for (int mf = 0; mf < 4; ++mf)
#pragma unroll
      for (int nf = 0; nf < 4; ++nf)
#pragma unroll
        for (int kh = 0; kh < 2; ++kh)
          acc[mf][nf] = __builtin_amdgcn_mfma_f32_16x16x32_bf16(
              afr[mf][kh], bfr[nf][kh], acc[mf][nf], 0, 0, 0);
  }

  // ---- fused LayerNorm(128) + leaky + mask epilogue ----
  float sv[4], qv[4];
#pragma unroll
  for (int nf = 0; nf < 4; ++nf) {
    float s = 0.f, sq = 0.f;
#pragma unroll
    for (int mf = 0; mf < 4; ++mf)
#pragma unroll
      for (int r = 0; r < 4; ++r) {
        float v = acc[mf][nf][r];
        s += v; sq += v * v;
      }
    s  += __shfl_xor(s, 16);  sq += __shfl_xor(sq, 16);
    s  += __shfl_xor(s, 32);  sq += __shfl_xor(sq, 32);
    sv[nf] = s; qv[nf] = sq;
  }
  if (lane < 16) {
#pragma unroll
    for (int nf = 0; nf < 4; ++nf) {
      lnS[wave][nf][lane] = sv[nf];
      lnQ[wave][nf][lane] = qv[nf];
    }
  }
  __syncthreads();

  float gr[4][4], br_[4][4];
#pragma unroll
  for (int mf = 0; mf < 4; ++mf) {
    int cb = wm + mf * 16 + ((lane >> 4) << 2);
    f32x4 gv = *reinterpret_cast<const f32x4*>(gamma + cb);
    f32x4 bv = *reinterpret_cast<const f32x4*>(beta + cb);
#pragma unroll
    for (int r = 0; r < 4; ++r) { gr[mf][r] = gv[r]; br_[mf][r] = bv[r]; }
  }

#pragma unroll
  for (int nf = 0; nf < 4; ++nf) {
    const float s  = sv[nf] + lnS[wave ^ 1][nf][lane & 15];
    const float sq = qv[nf] + lnQ[wave ^ 1][nf][lane & 15];
    const float mean = s * (1.f / 128.f);
    const float var  = sq * (1.f / 128.f) - mean * mean;
    const float rstd = rsqrtf(var + EPS);
    const int vox = n0 + wn + nf * 16 + (lane & 15);
    const float mk = msk[vox] ? 1.f : 0.f;
#pragma unroll
    for (int mf = 0; mf < 4; ++mf) {
      uint2 u;
      float r0 = (acc[mf][nf][0] - mean) * rstd * gr[mf][0] + br_[mf][0];
      float r1 = (acc[mf][nf][1] - mean) * rstd * gr[mf][1] + br_[mf][1];
      float r2 = (acc[mf][nf][2] - mean) * rstd * gr[mf][2] + br_[mf][2];
      float r3 = (acc[mf][nf][3] - mean) * rstd * gr[mf][3] + br_[mf][3];
      r0 = (r0 > 0.f ? r0 : SLOPE * r0) * mk;
      r1 = (r1 > 0.f ? r1 : SLOPE * r1) * mk;
      r2 = (r2 > 0.f ? r2 : SLOPE * r2) * mk;
      r3 = (r3 > 0.f ? r3 : SLOPE * r3) * mk;
      u.x = ((uint)f2bf(r1) << 16) | (uint)f2bf(r0);
      u.y = ((uint)f2bf(r3) << 16) | (uint)f2bf(r2);
      *reinterpret_cast<uint2*>(out + (size_t)vox * 128 + wm + mf * 16 +
                                ((lane >> 4) << 2)) = u;
    }
  }
}

// ---------------------------------------------------------------------------
// Implicit-GEMM conv (blocks 3-4): 128xBN tile, A+B LDS-staged, split-K.
// (R13-proven BN=64 config for under-occupied layers.)
// ---------------------------------------------------------------------------
template <int CIN, int COUT, int DIN, int S, int L2CIN, int SPLITK, int BN>
__global__ __launch_bounds__(256) void conv_gemm(
    const ushort* __restrict__ in,
    const ushort* __restrict__ wbf,
    float* __restrict__ rawout,
    const ushort* __restrict__ zpage)
{
  constexpr int W  = DIN / S;
  constexpr int K  = 27 * CIN;
  constexpr int NT = K / 64;
  constexpr int NTS = NT / SPLITK;
  constexpr int LW = (W == 32) ? 5 : (W == 16) ? 4 : 3;
  constexpr size_t NVOX = (size_t)2 * W * W * W;
  constexpr int NB = BN / 32;
  constexpr int NFC = BN / 32;

  const int t    = threadIdx.x;
  const int lane = t & 63;
  const int wave = t >> 6;
  const int n0   = blockIdx.x * BN;
  const int m0   = blockIdx.y * 128;
  const int kb0  = blockIdx.z * NTS;
  float* rawp = rawout + (size_t)blockIdx.z * NVOX * COUT;

  __shared__ short As[2][128 * 64];
  __shared__ short Bs[2][BN * 64];

  int aswz[4];
  const ushort* aptr[4];
#pragma unroll
  for (int j = 0; j < 4; ++j) {
    int q  = t + 256 * j;
    int ml = q >> 3, kc = q & 7;
    aswz[j] = ml * 64 + ((kc ^ (ml & 7)) << 3);
    aptr[j] = wbf + (size_t)(m0 + ml) * K + kc * 8;
  }
  int zb[NB], yb[NB], xb[NB], kc8[NB], bswz[NB];
  size_t bb[NB];
#pragma unroll
  for (int j = 0; j < NB; ++j) {
    int q  = t + 256 * j;
    int nl = q >> 3, kc = q & 7;
    kc8[j] = kc * 8;
    bswz[j] = nl * 64 + ((kc ^ (nl & 7)) << 3);
    int ng = n0 + nl;
    int xo = ng & (W - 1), yo = (ng >> LW) & (W - 1),
        zo = (ng >> (2 * LW)) & (W - 1), b = ng >> (3 * LW);
    xb[j] = xo * S; yb[j] = yo * S; zb[j] = zo * S;
    bb[j] = (size_t)b * CIN * DIN * DIN * DIN;
  }

  short8 ar[4], br[NB];

  auto LOADK = [&](int kb) {
    const int off = (kb * 64) >> L2CIN;
    const int ci0 = (kb * 64) & (CIN - 1);
    const int dz = off / 9, rr = off % 9;
    const int dy = rr / 3, dx = rr % 3;
#pragma unroll
    for (int j = 0; j < 4; ++j)
      ar[j] = *reinterpret_cast<const short8*>(aptr[j] + kb * 64);
#pragma unroll
    for (int j = 0; j < NB; ++j) {
      int zin = zb[j] + dz - 1;
      int yin = yb[j] + dy - 1;
      int xin = xb[j] + dx - 1;
      bool ok = ((unsigned)zin < (unsigned)DIN) &&
                ((unsigned)yin < (unsigned)DIN) &&
                ((unsigned)xin < (unsigned)DIN);
      const ushort* p = ok
          ? in + bb[j] + (((size_t)zin * DIN + yin) * DIN + xin) * CIN + ci0 + kc8[j]
          : zpage;
      br[j] = *reinterpret_cast<const short8*>(p);
    }
  };

  auto WRITEK = [&](int buf) {
#pragma unroll
    for (int j = 0; j < 4; ++j)
      *reinterpret_cast<short8*>(&As[buf][aswz[j]]) = ar[j];
#pragma unroll
    for (int j = 0; j < NB; ++j)
      *reinterpret_cast<short8*>(&Bs[buf][bswz[j]]) = br[j];
  };

  f32x4 acc[4][NFC];
#pragma unroll
  for (int i = 0; i < 4; ++i)
#pragma unroll
    for (int j = 0; j < NFC; ++j) acc[i][j] = (f32x4)(0.f);

  const int wm = (wave & 1) * 64;
  const int wn = (wave >> 1) * (BN / 2);

  LOADK(kb0);
  for (int kb = kb0; kb < kb0 + NTS; ++kb) {
    const int buf = (kb - kb0) & 1;
    WRITEK(buf);
    if (kb + 1 < kb0 + NTS) LOADK(kb + 1);
    __syncthreads();

    short8 afr[4][2], bfr[NFC][2];
#pragma unroll
    for (int mf = 0; mf < 4; ++mf)
#pragma unroll
      for (int kh = 0; kh < 2; ++kh) {
        int row  = wm + mf * 16 + (lane & 15);
        int slot = (lane >> 4) + kh * 4;
        afr[mf][kh] = *reinterpret_cast<const short8*>(
            &As[buf][row * 64 + ((slot ^ (row & 7)) << 3)]);
      }
#pragma unroll
    for (int nf = 0; nf < NFC; ++nf)
#pragma unroll
      for (int kh = 0; kh < 2; ++kh) {
        int row  = wn + nf * 16 + (lane & 15);
        int slot = (lane >> 4) + kh * 4;
        bfr[nf][kh] = *reinterpret_cast<const short8*>(
            &Bs[buf][row * 64 + ((slot ^ (row & 7)) << 3)]);
      }
#pragma unroll
    for (int mf = 0; mf < 4; ++mf)
#pragma unroll
      for (int nf = 0; nf < NFC; ++nf)
#pragma unroll
        for (int kh = 0; kh < 2; ++kh)
          acc[mf][nf] = __builtin_amdgcn_mfma_f32_16x16x32_bf16(
              afr[mf][kh], bfr[nf][kh], acc[mf][nf], 0, 0, 0);
  }

#pragma unroll
  for (int mf = 0; mf < 4; ++mf)
#pragma unroll
    for (int nf = 0; nf < NFC; ++nf) {
      int mg = m0 + wm + mf * 16 + ((lane >> 4) << 2);
      int ng = n0 + wn + nf * 16 + (lane & 15);
      *reinterpret_cast<f32x4*>(&rawp[(size_t)ng * COUT + mg]) = acc[mf][nf];
    }
}

// ---------------------------------------------------------------------------
// LayerNorm + LeakyReLU + mask (sums NPART split-K partials). Wave per voxel.
// ---------------------------------------------------------------------------
template <int C, int NPART, bool BF16OUT>
__global__ __launch_bounds__(256) void ln_mask_k(
    const float* __restrict__ raw,
    const float* __restrict__ gamma,
    const float* __restrict__ beta,
    const uint8_t* __restrict__ msk,
    void* __restrict__ outv, int nvox)
{
  constexpr int E = C / 64;
  const int lane = threadIdx.x & 63;
  const int vox  = blockIdx.x * 4 + (threadIdx.x >> 6);
  if (vox >= nvox) return;

  const size_t stride = (size_t)nvox * C;
  const float* p = raw + (size_t)vox * C;
  float v[E];
  float s = 0.f, sq = 0.f;
#pragma unroll
  for (int e = 0; e < E; ++e) {
    float acc = 0.f;
#pragma unroll
    for (int pt = 0; pt < NPART; ++pt) acc += p[pt * stride + e * 64 + lane];
    v[e] = acc;
    s += acc; sq += acc * acc;
  }
#pragma unroll
  for (int off = 32; off; off >>= 1) {
    s  += __shfl_xor(s, off);
    sq += __shfl_xor(sq, off);
  }
  const float mean = s / (float)C;
  const float var  = sq / (float)C - mean * mean;
  const float rstd = rsqrtf(var + EPS);
  const float mk   = msk[vox] ? 1.f : 0.f;

#pragma unroll
  for (int e = 0; e < E; ++e) {
    int c = e * 64 + lane;
    float r = (v[e] - mean) * rstd * gamma[c] + beta[c];
    r = (r > 0.f ? r : SLOPE * r) * mk;
    if (BF16OUT)
      ((ushort*)outv)[(size_t)vox * C + c] = f2bf(r);
    else
      ((float*)outv)[(size_t)vox * C + c] = r;
  }
}

// ---------------------------------------------------------------------------
// Block4 LN + leaky + mask + per-group max + FUSED final max.
// ---------------------------------------------------------------------------
template <int NPART>
__global__ __launch_bounds__(256) void ln4max_k(
    const float* __restrict__ raw,      // [NPART][1024][512]
    const float* __restrict__ gamma,
    const float* __restrict__ beta,
    const uint8_t* __restrict__ msk,    // [1024]
    float* __restrict__ pm,             // [16][512]
    unsigned* __restrict__ cnt,         // zeroed each launch
    float* __restrict__ out)            // [2][512]
{
  const int t    = threadIdx.x;
  const int lane = t & 63;
  const int wave = t >> 6;
  const int grp  = blockIdx.x;          // 0..15
  const size_t stride = (size_t)1024 * 512;

  float gg[8], bb_[8];
#pragma unroll
  for (int e = 0; e < 8; ++e) {
    int c = e * 64 + lane;
    gg[e] = gamma[c]; bb_[e] = beta[c];
  }

  float vmax[8];
#pragma unroll
  for (int e = 0; e < 8; ++e) vmax[e] = -1e30f;

  for (int it = 0; it < 16; ++it) {
    const int vox = grp * 64 + wave * 16 + it;
    const float* p = raw + (size_t)vox * 512;
    float v[8];
    float s = 0.f, sq = 0.f;
#pragma unroll
    for (int e = 0; e < 8; ++e) {
      float a = 0.f;
#pragma unroll
      for (int pt = 0; pt < NPART; ++pt) a += p[pt * stride + e * 64 + lane];
      v[e] = a; s += a; sq += a * a;
    }
#pragma unroll
    for (int off = 32; off; off >>= 1) {
      s  += __shfl_xor(s, off);
      sq += __shfl_xor(sq, off);
    }
    const float mean = s * (1.f / 512.f);
    const float var  = sq * (1.f / 512.f) - mean * mean;
    const float rstd = rsqrtf(var + EPS);
    const float mk   = msk[vox] ? 1.f : 0.f;
#pragma unroll
    for (int e = 0; e < 8; ++e) {
      float r = (v[e] - mean) * rstd * gg[e] + bb_[e];
      r = (r > 0.f ? r : SLOPE * r) * mk;
      vmax[e] = fmaxf(vmax[e], r);
    }
  }

  __shared__ float red[4][512];
#pragma unroll
  for (int e = 0; e < 8; ++e) red[wave][e * 64 + lane] = vmax[e];
  __syncthreads();
  for (int c = t; c < 512; c += 256) {
    float m = fmaxf(fmaxf(red[0][c], red[1][c]), fmaxf(red[2][c], red[3][c]));
    pm[(size_t)grp * 512 + c] = m;
  }

  __threadfence();
  __shared__ unsigned isLast;
  if (t == 0) isLast = atomicAdd(cnt, 1u);
  __syncthreads();
  if (isLast == 15) {
    __threadfence();
    for (int i = t; i < 1024; i += 256) {      // i = b*512 + c
      int b = i >> 9, c = i & 511;
      float m = -1e30f;
#pragma unroll
      for (int g = 0; g < 8; ++g)
        m = fmaxf(m, pm[((size_t)b * 8 + g) * 512 + c]);
      out[i] = m;
    }
  }
}

// ---------------------------------------------------------------------------
extern "C" void kernel_launch(void* const* d_in, const int* in_sizes, int n_in,
                              void* d_out, int out_size, void* d_ws, size_t ws_size,
                              hipStream_t stream) {
  const float*   x    = (const float*)d_in[0];
  const uint8_t* mraw = (const uint8_t*)d_in[1];
  const float* w1 = (const float*)d_in[2];
  const float* g1 = (const float*)d_in[3];
  const float* b1 = (const float*)d_in[4];
  const float* w2 = (const float*)d_in[5];
  const float* g2 = (const float*)d_in[6];
  const float* b2 = (const float*)d_in[7];
  const float* w3 = (const float*)d_in[8];
  const float* g3 = (const float*)d_in[9];
  const float* b3 = (const float*)d_in[10];
  const float* w4 = (const float*)d_in[11];
  const float* g4 = (const float*)d_in[12];
  const float* b4 = (const float*)d_in[13];
  float* out = (float*)d_out;
  char*  ws  = (char*)d_ws;

  const size_t ZP   = 0;
  const size_t T1   = 256;
  const size_t R3b  = 67109120;
  const size_t T2   = 92274944;
  const size_t T3   = 109052160;
  const size_t PM   = 113246464;
  const size_t XCLP = 113279232;
  const size_t XCLP_BYTES = 4600064;
  const size_t WB1  = XCLP + XCLP_BYTES;
  const size_t WB2  = WB1 + 16384;
  const size_t WB3  = WB2 + 442368;
  const size_t WB4  = WB3 + 1769472;
  const size_t M1   = WB4 + 7077888;
  const size_t M2   = M1 + 524288;
  const size_t M3   = M2 + 65536;
  const size_t M4   = M3 + 8192;

  unsigned* flag = (unsigned*)(ws + ZP);
  unsigned* cnt  = (unsigned*)(ws + ZP + 4);
  const ushort* zpage = (const ushort*)(ws + ZP + 16);
  ushort* t1   = (ushort*)(ws + T1);
  float*  r3   = (float*)(ws + R3b);
  float*  r4   = (float*)(ws + R3b + 16777216);
  ushort* t2   = (ushort*)(ws + T2);
  ushort* t3   = (ushort*)(ws + T3);
  float*  pm   = (float*)(ws + PM);
  ushort* xclp = (ushort*)(ws + XCLP);
  ushort* wb1  = (ushort*)(ws + WB1);
  ushort* wb2  = (ushort*)(ws + WB2);
  ushort* wb3  = (ushort*)(ws + WB3);
  ushort* wb4  = (ushort*)(ws + WB4);
  uint8_t* m1  = (uint8_t*)(ws + M1);
  uint8_t* m2  = (uint8_t*)(ws + M2);
  uint8_t* m3  = (uint8_t*)(ws + M3);
  uint8_t* m4  = (uint8_t*)(ws + M4);

  const int NM1 = 2 * 64 * 64 * 64;

  hipMemsetAsync(ws + ZP, 0, 64, stream);
  zdetect_k<<<1124 + 256, 256, 0, stream>>>(
      (uint4*)(ws + XCLP), (int)(XCLP_BYTES / 16), mraw, NM1, flag);
  xclm_k<<<NM1 / 256, 256, 0, stream>>>(x, mraw, flag, m1, xclp);

  prep2_k<<<1189, 256, 0, stream>>>(w1, w2, w3, w4, wb1, wb2, wb3, wb4,
                                    m1, m2, m3, m4);

  conv1_gemm<<<512, 512, 0, stream>>>(xclp, wb1, g1, b1, m1, t1);

  conv2_gemm<<<512, 256, 0, stream>>>(t1, wb2, g2, b2, m2, t2, zpage);

  conv_gemm<128, 256, 32, 2, 7, 2, 64><<<dim3(128, 2, 2), 256, 0, stream>>>(
      t2, wb3, r3, zpage);
  ln_mask_k<256, 2, true><<<8192 / 4, 256, 0, stream>>>(r3, g3, b3, m3, t3, 8192);

  conv_gemm<256, 512, 16, 2, 8, 4, 64><<<dim3(16, 4, 4), 256, 0, stream>>>(
      t3, wb4, r4, zpage);
  ln4max_k<4><<<16, 256, 0, stream>>>(r4, g4, b4, m4, pm, cnt, out);

  (void)in_sizes; (void)n_in; (void)out_size; (void)ws_size;
}

// Round 23
// 164.393 us; speedup vs baseline: 1.0127x; 1.0127x over previous
//
#include <hip/hip_runtime.h>
#include <hip/hip_bf16.h>
#include <stdint.h>

#define EPS 1e-5f
#define SLOPE 0.2f

typedef __attribute__((ext_vector_type(8))) short short8;
typedef __attribute__((ext_vector_type(4))) float f32x4;

static __device__ inline ushort f2bf(float f) {
  __hip_bfloat16 h = __float2bfloat16(f);
  return *reinterpret_cast<ushort*>(&h);
}

static __device__ inline short8 u4_to_s8(uint a, uint b, uint c, uint d) {
  union { uint4 u; short8 s; } cv;
  cv.u.x = a; cv.u.y = b; cv.u.z = c; cv.u.w = d;
  return cv.s;
}

// ---------------------------------------------------------------------------
// Fused: zero XCLP halo (blocks [0,1124)) + mask dtype detection (rest).
// ---------------------------------------------------------------------------
__global__ void zdetect_k(uint4* __restrict__ zp, int n16,
                          const uint8_t* __restrict__ raw, int nbytes,
                          unsigned* __restrict__ flag) {
  int bid = blockIdx.x;
  if (bid < 1124) {
    int i = bid * 256 + threadIdx.x;
    if (i < n16) zp[i] = make_uint4(0u, 0u, 0u, 0u);
    return;
  }
  unsigned local = 0;
  for (int i = (bid - 1124) * 256 + threadIdx.x; i < nbytes; i += 256 * 256)
    if (i & 3) local |= raw[i];
  if (local) atomicOr(flag, 1u);
}

// Fused mask-convert + input pack into PADDED [2][66][66][66][4] bf16.
__global__ void xclm_k(const float* __restrict__ x, const uint8_t* __restrict__ raw,
                       const unsigned* __restrict__ flag,
                       uint8_t* __restrict__ m1, ushort* __restrict__ xclp) {
  int id = blockIdx.x * blockDim.x + threadIdx.x;
  if (id >= 2 * 262144) return;
  uint8_t v;
  if (*flag) {
    v = raw[id];
  } else {
    size_t j = 4 * (size_t)id;
    v = (uint8_t)(raw[j] | raw[j + 1] | raw[j + 2] | raw[j + 3]);
  }
  v = v ? 1 : 0;
  m1[id] = v;
  float mk = (float)v;
  int b  = id >> 18;
  int sp = id & 262143;
  int xx = sp & 63, yy = (sp >> 6) & 63, zz = sp >> 12;
  size_t base = (size_t)b * 3 * 262144 + sp;
  float x0 = x[base] * mk;
  float x1 = x[base + 262144] * mk;
  float x2 = x[base + 2 * 262144] * mk;
  uint2 u;
  u.x = ((uint)f2bf(x1) << 16) | (uint)f2bf(x0);
  u.y = (uint)f2bf(x2);
  size_t pidx = ((((size_t)(b * 66 + zz + 1)) * 66 + (yy + 1)) * 66 + (xx + 1)) * 4;
  *reinterpret_cast<uint2*>(xclp + pidx) = u;
}

// ---------------------------------------------------------------------------
// Fused prep v2: LDS-tiled per-row weight transposes + wb1 + mask pyramid.
// ---------------------------------------------------------------------------
__global__ __launch_bounds__(256) void prep2_k(
    const float* __restrict__ w1, const float* __restrict__ w2,
    const float* __restrict__ w3, const float* __restrict__ w4,
    ushort* __restrict__ wb1, ushort* __restrict__ wb2,
    ushort* __restrict__ wb3, ushort* __restrict__ wb4,
    const uint8_t* __restrict__ m1, uint8_t* __restrict__ m2,
    uint8_t* __restrict__ m3, uint8_t* __restrict__ m4) {
  __shared__ ushort ls[6912];
  const int t   = threadIdx.x;
  const int bid = blockIdx.x;

  if (bid < 896) {
    const float* w; ushort* wb; int c, K, l2c;
    if (bid < 512)      { w = w4; wb = wb4; c = bid;       K = 6912; l2c = 8; }
    else if (bid < 768) { w = w3; wb = wb3; c = bid - 512; K = 3456; l2c = 7; }
    else                { w = w2; wb = wb2; c = bid - 768; K = 1728; l2c = 6; }
    const float* src = w + (size_t)c * K;
    for (int i = t; i < K; i += 256) ls[i] = f2bf(src[i]);
    __syncthreads();
    ushort* dst = wb + (size_t)c * K;
    const int cm = (1 << l2c) - 1;
    for (int kn = t; kn < K; kn += 256) {
      int off = kn >> l2c, ci = kn & cm;
      dst[kn] = ls[ci * 27 + off];
    }
    return;
  }
  if (bid == 896) {
    for (int id = t; id < 8192; id += 256) {
      int k = id & 127, c = id >> 7;
      int tap = k >> 2, ci = k & 3;
      float v = (tap < 27 && ci < 3) ? w1[c * 81 + ci * 27 + tap] : 0.f;
      wb1[id] = f2bf(v);
    }
    return;
  }
  int id = (bid - 897) * 256 + t;
  if (id >= 74752) return;
  int Wl, rad, sh;
  uint8_t* mo;
  if (id < 65536)      { Wl = 32; rad = 1; sh = 1; mo = m2; }
  else if (id < 73728) { id -= 65536; Wl = 16; rad = 3; sh = 2; mo = m3; }
  else                 { id -= 73728; Wl = 8;  rad = 7; sh = 3; mo = m4; }
  int xo = id % Wl; int tt = id / Wl;
  int yo = tt % Wl; tt /= Wl;
  int zo = tt % Wl; int b = tt / Wl;
  int cx = xo << sh, cy = yo << sh, cz = zo << sh;
  int zlo = max(cz - rad, 0), zhi = min(cz + rad, 63);
  int ylo = max(cy - rad, 0), yhi = min(cy + rad, 63);
  int xlo = max(cx - rad, 0), xhi = min(cx + rad, 63);
  int any = 0;
  for (int z = zlo; z <= zhi && !any; ++z)
    for (int y = ylo; y <= yhi && !any; ++y)
      for (int x = xlo; x <= xhi; ++x)
        any |= m1[(((size_t)b * 64 + z) * 64 + y) * 64 + x];
  mo[(((size_t)b * Wl + zo) * Wl + yo) * Wl + xo] = any ? 1 : 0;
}

// ---------------------------------------------------------------------------
// Block1 GEMM via LDS spatial tile: 512 threads (8 waves), 8 z-slices per
// block, wb1 staged once into LDS (R19/R21-proven best).
// ---------------------------------------------------------------------------
__global__ __launch_bounds__(512) void conv1_gemm(
    const ushort* __restrict__ xclp,    // [2][66][66][66][4] bf16, zero halo
    const ushort* __restrict__ wb1,     // [64][128] bf16
    const float* __restrict__ gamma,
    const float* __restrict__ beta,
    const uint8_t* __restrict__ msk,    // [2*64^3]
    ushort* __restrict__ out)           // [2*64^3][64] bf16
{
  const int t    = threadIdx.x;
  const int lane = t & 63;
  const int wave = t >> 6;
  const int wv   = wave & 3;
  const int grp  = wave >> 2;
  const int c8   = lane >> 4;

  const int bid = blockIdx.x;           // 512 = 2*8*32
  const int yp = bid & 31;
  const int zo = (bid >> 5) & 7;
  const int b  = bid >> 8;
  const int y0 = yp * 2;
  const int z0 = zo * 8;

  __shared__ uint2 tile[2640];          // [p 0..9][r 0..3][x 0..65]
  __shared__ ushort wlds[64 * 136];     // wb1 rows padded to 136

  const uint2* xin = reinterpret_cast<const uint2*>(xclp);
  const long gbase = (((long)(b * 66 + z0)) * 66 + y0) * 66;
  for (int e = t; e < 2640; e += 512) {
    int p = e / 264;
    tile[e] = xin[gbase + e + p * 4092];
  }
  for (int e = t; e < 8192; e += 512) {
    int row = e >> 7, k = e & 127;
    wlds[row * 136 + k] = wb1[e];
  }

  int eoff[2][2][2];
#pragma unroll
  for (int kb = 0; kb < 2; ++kb)
#pragma unroll
    for (int kh = 0; kh < 2; ++kh)
#pragma unroll
      for (int p = 0; p < 2; ++p) {
        int tap = kb * 16 + kh * 8 + c8 * 2 + p;
        int off = 0;
        if (tap < 27) {
          int dz = tap / 9, rr = tap - dz * 9;
          int dy = rr / 3, dx = rr - dy * 3;
          off = dz * 264 + dy * 66 + dx;
        }
        eoff[kb][kh][p] = off;
      }

  int ebase[2];
#pragma unroll
  for (int nf = 0; nf < 2; ++nf) {
    int nl = wv * 32 + nf * 16 + (lane & 15);
    ebase[nf] = (nl >> 6) * 66 + (nl & 63);
  }

  float gr[4][4], br_[4][4];
#pragma unroll
  for (int mf = 0; mf < 4; ++mf) {
    int cb = mf * 16 + c8 * 4;
    f32x4 gv  = *reinterpret_cast<const f32x4*>(gamma + cb);
    f32x4 bv2 = *reinterpret_cast<const f32x4*>(beta + cb);
#pragma unroll
    for (int r = 0; r < 4; ++r) { gr[mf][r] = gv[r]; br_[mf][r] = bv2[r]; }
  }

  __syncthreads();

  for (int zz = 0; zz < 4; ++zz) {
    const int zi  = 2 * zz + grp;
    const int zsh = zi * 264;
    f32x4 acc[4][2];
#pragma unroll
    for (int i = 0; i < 4; ++i)
#pragma unroll
      for (int j = 0; j < 2; ++j) acc[i][j] = (f32x4)(0.f);

#pragma unroll
    for (int kb = 0; kb < 2; ++kb) {
      short8 afr[4][2];
#pragma unroll
      for (int mf = 0; mf < 4; ++mf)
#pragma unroll
        for (int kh = 0; kh < 2; ++kh) {
          int row = mf * 16 + (lane & 15);
          int k   = kb * 64 + (c8 + kh * 4) * 8;
          afr[mf][kh] = *reinterpret_cast<const short8*>(&wlds[row * 136 + k]);
        }
#pragma unroll
      for (int nf = 0; nf < 2; ++nf)
#pragma unroll
        for (int kh = 0; kh < 2; ++kh) {
          uint2 v0 = tile[ebase[nf] + zsh + eoff[kb][kh][0]];
          uint2 v1 = tile[ebase[nf] + zsh + eoff[kb][kh][1]];
          short8 bfr = u4_to_s8(v0.x, v0.y, v1.x, v1.y);
#pragma unroll
          for (int mf = 0; mf < 4; ++mf)
            acc[mf][nf] = __builtin_amdgcn_mfma_f32_16x16x32_bf16(
                afr[mf][kh], bfr, acc[mf][nf], 0, 0, 0);
        }
    }

    const int z = z0 + zi;
    const int voxbase = ((b * 64 + z) * 64 + y0) * 64;
#pragma unroll
    for (int nf = 0; nf < 2; ++nf) {
      float s = 0.f, sq = 0.f;
#pragma unroll
      for (int mf = 0; mf < 4; ++mf)
#pragma unroll
        for (int r = 0; r < 4; ++r) {
          float v = acc[mf][nf][r];
          s += v; sq += v * v;
        }
      s  += __shfl_xor(s, 16);  sq += __shfl_xor(sq, 16);
      s  += __shfl_xor(s, 32);  sq += __shfl_xor(sq, 32);
      const float mean = s * (1.f / 64.f);
      const float var  = sq * (1.f / 64.f) - mean * mean;
      const float rstd = rsqrtf(var + EPS);
      const int vox = voxbase + wv * 32 + nf * 16 + (lane & 15);
      const float mk = msk[vox] ? 1.f : 0.f;
#pragma unroll
      for (int mf = 0; mf < 4; ++mf) {
        uint2 u;
        float r0 = (acc[mf][nf][0] - mean) * rstd * gr[mf][0] + br_[mf][0];
        float r1 = (acc[mf][nf][1] - mean) * rstd * gr[mf][1] + br_[mf][1];
        float r2 = (acc[mf][nf][2] - mean) * rstd * gr[mf][2] + br_[mf][2];
        float r3 = (acc[mf][nf][3] - mean) * rstd * gr[mf][3] + br_[mf][3];
        r0 = (r0 > 0.f ? r0 : SLOPE * r0) * mk;
        r1 = (r1 > 0.f ? r1 : SLOPE * r1) * mk;
        r2 = (r2 > 0.f ? r2 : SLOPE * r2) * mk;
        r3 = (r3 > 0.f ? r3 : SLOPE * r3) * mk;
        u.x = ((uint)f2bf(r1) << 16) | (uint)f2bf(r0);
        u.y = ((uint)f2bf(r3) << 16) | (uint)f2bf(r2);
        *reinterpret_cast<uint2*>(out + (size_t)vox * 64 + mf * 16 + c8 * 4) = u;
      }
    }
  }
}

// ---------------------------------------------------------------------------
// Block2: LDS double-buffered implicit GEMM 64->128 s2, FUSED LN epilogue.
// (R9-proven BN=128: A+B both LDS-staged.)
// ---------------------------------------------------------------------------
__global__ __launch_bounds__(256) void conv2_gemm(
    const ushort* __restrict__ in,      // t1 [524288][64] bf16
    const ushort* __restrict__ wbf,     // wb2 [128][1728] bf16
    const float* __restrict__ gamma,
    const float* __restrict__ beta,
    const uint8_t* __restrict__ msk,    // m2 [65536]
    ushort* __restrict__ out,           // t2 [65536][128] bf16
    const ushort* __restrict__ zpage)
{
  constexpr int CIN = 64, DIN = 64, S = 2;
  constexpr int W = 32, K = 1728, NT = 27, LW = 5;

  const int t    = threadIdx.x;
  const int lane = t & 63;
  const int wave = t >> 6;
  int bid = blockIdx.x;
  bid = (bid & 7) * 64 + (bid >> 3);        // XCD swizzle (512 = 8*64)
  const int n0 = bid * 128;

  __shared__ short As[2][128 * 64];
  __shared__ short Bs[2][128 * 64];
  __shared__ float lnS[4][4][16];
  __shared__ float lnQ[4][4][16];

  int zb[4], yb[4], xb[4], kc8[4], swz[4];
  size_t bb[4];
  const ushort* aptr[4];
#pragma unroll
  for (int j = 0; j < 4; ++j) {
    int q  = t + 256 * j;
    int nl = q >> 3, kc = q & 7;
    kc8[j] = kc * 8;
    swz[j] = nl * 64 + ((kc ^ (nl & 7)) << 3);
    int ngv = n0 + nl;
    int xo = ngv & (W - 1), yo = (ngv >> LW) & (W - 1),
        zo = (ngv >> (2 * LW)) & (W - 1), b = ngv >> (3 * LW);
    xb[j] = xo * S; yb[j] = yo * S; zb[j] = zo * S;
    bb[j] = (size_t)b * CIN * DIN * DIN * DIN;
    aptr[j] = wbf + (size_t)nl * K + kc * 8;
  }

  short8 ar[4], br[4];

  auto LOADK = [&](int kb) {
    const int off = kb;                      // 64 k = 1 tap (CIN=64)
    const int dz = off / 9, rr = off % 9;
    const int dy = rr / 3, dx = rr % 3;
#pragma unroll
    for (int j = 0; j < 4; ++j) {
      ar[j] = *reinterpret_cast<const short8*>(aptr[j] + kb * 64);
      int zin = zb[j] + dz - 1;
      int yin = yb[j] + dy - 1;
      int xin = xb[j] + dx - 1;
      bool ok = ((unsigned)zin < (unsigned)DIN) &&
                ((unsigned)yin < (unsigned)DIN) &&
                ((unsigned)xin < (unsigned)DIN);
      const ushort* p = ok
          ? in + bb[j] + (((size_t)zin * DIN + yin) * DIN + xin) * CIN + kc8[j]
          : zpage;
      br[j] = *reinterpret_cast<const short8*>(p);
    }
  };

  auto WRITEK = [&](int buf) {
#pragma unroll
    for (int j = 0; j < 4; ++j) {
      *reinterpret_cast<short8*>(&As[buf][swz[j]]) = ar[j];
      *reinterpret_cast<short8*>(&Bs[buf][swz[j]]) = br[j];
    }
  };

  f32x4 acc[4][4];
#pragma unroll
  for (int i = 0; i < 4; ++i)
#pragma unroll
    for (int j = 0; j < 4; ++j) acc[i][j] = (f32x4)(0.f);

  const int wm = (wave & 1) * 64;
  const int wn = (wave >> 1) * 64;

  LOADK(0);
  for (int kb = 0; kb < NT; ++kb) {
    const int buf = kb & 1;
    WRITEK(buf);
    if (kb + 1 < NT) LOADK(kb + 1);
    __syncthreads();

    short8 afr[4][2], bfr[4][2];
#pragma unroll
    for (int mf = 0; mf < 4; ++mf)
#pragma unroll
      for (int kh = 0; kh < 2; ++kh) {
        int row  = wm + mf * 16 + (lane & 15);
        int slot = (lane >> 4) + kh * 4;
        afr[mf][kh] = *reinterpret_cast<const short8*>(
            &As[buf][row * 64 + ((slot ^ (row & 7)) << 3)]);
      }
#pragma unroll
    for (int nf = 0; nf < 4; ++nf)
#pragma unroll
      for (int kh = 0; kh < 2; ++kh) {
        int row  = wn + nf * 16 + (lane & 15);
        int slot = (lane >> 4) + kh * 4;
        bfr[nf][kh] = *reinterpret_cast<const short8*>(
            &Bs[buf][row * 64 + ((slot ^ (row & 7)) << 3)]);
      }
#pragma unroll
    for (int mf = 0; mf < 4; ++mf)
#pragma unroll
      for (int nf = 0; nf < 4; ++nf)
#pragma unroll
        for (int kh = 0; kh < 2; ++kh)
          acc[mf][nf] = __builtin_amdgcn_mfma_f32_16x16x32_bf16(
              afr[mf][kh], bfr[nf][kh], acc[mf][nf], 0, 0, 0);
  }

  // ---- fused LayerNorm(128) + leaky + mask epilogue ----
  float sv[4], qv[4];
#pragma unroll
  for (int nf = 0; nf < 4; ++nf) {
    float s = 0.f, sq = 0.f;
#pragma unroll
    for (int mf = 0; mf < 4; ++mf)
#pragma unroll
      for (int r = 0; r < 4; ++r) {
        float v = acc[mf][nf][r];
        s += v; sq += v * v;
      }
    s  += __shfl_xor(s, 16);  sq += __shfl_xor(sq, 16);
    s  += __shfl_xor(s, 32);  sq += __shfl_xor(sq, 32);
    sv[nf] = s; qv[nf] = sq;
  }
  if (lane < 16) {
#pragma unroll
    for (int nf = 0; nf < 4; ++nf) {
      lnS[wave][nf][lane] = sv[nf];
      lnQ[wave][nf][lane] = qv[nf];
    }
  }
  __syncthreads();

  float gr[4][4], br_[4][4];
#pragma unroll
  for (int mf = 0; mf < 4; ++mf) {
    int cb = wm + mf * 16 + ((lane >> 4) << 2);
    f32x4 gv = *reinterpret_cast<const f32x4*>(gamma + cb);
    f32x4 bv = *reinterpret_cast<const f32x4*>(beta + cb);
#pragma unroll
    for (int r = 0; r < 4; ++r) { gr[mf][r] = gv[r]; br_[mf][r] = bv[r]; }
  }

#pragma unroll
  for (int nf = 0; nf < 4; ++nf) {
    const float s  = sv[nf] + lnS[wave ^ 1][nf][lane & 15];
    const float sq = qv[nf] + lnQ[wave ^ 1][nf][lane & 15];
    const float mean = s * (1.f / 128.f);
    const float var  = sq * (1.f / 128.f) - mean * mean;
    const float rstd = rsqrtf(var + EPS);
    const int vox = n0 + wn + nf * 16 + (lane & 15);
    const float mk = msk[vox] ? 1.f : 0.f;
#pragma unroll
    for (int mf = 0; mf < 4; ++mf) {
      uint2 u;
      float r0 = (acc[mf][nf][0] - mean) * rstd * gr[mf][0] + br_[mf][0];
      float r1 = (acc[mf][nf][1] - mean) * rstd * gr[mf][1] + br_[mf][1];
      float r2 = (acc[mf][nf][2] - mean) * rstd * gr[mf][2] + br_[mf][2];
      float r3 = (acc[mf][nf][3] - mean) * rstd * gr[mf][3] + br_[mf][3];
      r0 = (r0 > 0.f ? r0 : SLOPE * r0) * mk;
      r1 = (r1 > 0.f ? r1 : SLOPE * r1) * mk;
      r2 = (r2 > 0.f ? r2 : SLOPE * r2) * mk;
      r3 = (r3 > 0.f ? r3 : SLOPE * r3) * mk;
      u.x = ((uint)f2bf(r1) << 16) | (uint)f2bf(r0);
      u.y = ((uint)f2bf(r3) << 16) | (uint)f2bf(r2);
      *reinterpret_cast<uint2*>(out + (size_t)vox * 128 + wm + mf * 16 +
                                ((lane >> 4) << 2)) = u;
    }
  }
}

// ---------------------------------------------------------------------------
// Implicit-GEMM conv (blocks 3-4): 128xBN tile, A+B LDS-staged, split-K.
// (R13-proven BN=64 config for under-occupied layers.)
// ---------------------------------------------------------------------------
template <int CIN, int COUT, int DIN, int S, int L2CIN, int SPLITK, int BN>
__global__ __launch_bounds__(256) void conv_gemm(
    const ushort* __restrict__ in,
    const ushort* __restrict__ wbf,
    float* __restrict__ rawout,
    const ushort* __restrict__ zpage)
{
  constexpr int W  = DIN / S;
  constexpr int K  = 27 * CIN;
  constexpr int NT = K / 64;
  constexpr int NTS = NT / SPLITK;
  constexpr int LW = (W == 32) ? 5 : (W == 16) ? 4 : 3;
  constexpr size_t NVOX = (size_t)2 * W * W * W;
  constexpr int NB = BN / 32;
  constexpr int NFC = BN / 32;

  const int t    = threadIdx.x;
  const int lane = t & 63;
  const int wave = t >> 6;
  const int n0   = blockIdx.x * BN;
  const int m0   = blockIdx.y * 128;
  const int kb0  = blockIdx.z * NTS;
  float* rawp = rawout + (size_t)blockIdx.z * NVOX * COUT;

  __shared__ short As[2][128 * 64];
  __shared__ short Bs[2][BN * 64];

  int aswz[4];
  const ushort* aptr[4];
#pragma unroll
  for (int j = 0; j < 4; ++j) {
    int q  = t + 256 * j;
    int ml = q >> 3, kc = q & 7;
    aswz[j] = ml * 64 + ((kc ^ (ml & 7)) << 3);
    aptr[j] = wbf + (size_t)(m0 + ml) * K + kc * 8;
  }
  int zb[NB], yb[NB], xb[NB], kc8[NB], bswz[NB];
  size_t bb[NB];
#pragma unroll
  for (int j = 0; j < NB; ++j) {
    int q  = t + 256 * j;
    int nl = q >> 3, kc = q & 7;
    kc8[j] = kc * 8;
    bswz[j] = nl * 64 + ((kc ^ (nl & 7)) << 3);
    int ng = n0 + nl;
    int xo = ng & (W - 1), yo = (ng >> LW) & (W - 1),
        zo = (ng >> (2 * LW)) & (W - 1), b = ng >> (3 * LW);
    xb[j] = xo * S; yb[j] = yo * S; zb[j] = zo * S;
    bb[j] = (size_t)b * CIN * DIN * DIN * DIN;
  }

  short8 ar[4], br[NB];

  auto LOADK = [&](int kb) {
    const int off = (kb * 64) >> L2CIN;
    const int ci0 = (kb * 64) & (CIN - 1);
    const int dz = off / 9, rr = off % 9;
    const int dy = rr / 3, dx = rr % 3;
#pragma unroll
    for (int j = 0; j < 4; ++j)
      ar[j] = *reinterpret_cast<const short8*>(aptr[j] + kb * 64);
#pragma unroll
    for (int j = 0; j < NB; ++j) {
      int zin = zb[j] + dz - 1;
      int yin = yb[j] + dy - 1;
      int xin = xb[j] + dx - 1;
      bool ok = ((unsigned)zin < (unsigned)DIN) &&
                ((unsigned)yin < (unsigned)DIN) &&
                ((unsigned)xin < (unsigned)DIN);
      const ushort* p = ok
          ? in + bb[j] + (((size_t)zin * DIN + yin) * DIN + xin) * CIN + ci0 + kc8[j]
          : zpage;
      br[j] = *reinterpret_cast<const short8*>(p);
    }
  };

  auto WRITEK = [&](int buf) {
#pragma unroll
    for (int j = 0; j < 4; ++j)
      *reinterpret_cast<short8*>(&As[buf][aswz[j]]) = ar[j];
#pragma unroll
    for (int j = 0; j < NB; ++j)
      *reinterpret_cast<short8*>(&Bs[buf][bswz[j]]) = br[j];
  };

  f32x4 acc[4][NFC];
#pragma unroll
  for (int i = 0; i < 4; ++i)
#pragma unroll
    for (int j = 0; j < NFC; ++j) acc[i][j] = (f32x4)(0.f);

  const int wm = (wave & 1) * 64;
  const int wn = (wave >> 1) * (BN / 2);

  LOADK(kb0);
  for (int kb = kb0; kb < kb0 + NTS; ++kb) {
    const int buf = (kb - kb0) & 1;
    WRITEK(buf);
    if (kb + 1 < kb0 + NTS) LOADK(kb + 1);
    __syncthreads();

    short8 afr[4][2], bfr[NFC][2];
#pragma unroll
    for (int mf = 0; mf < 4; ++mf)
#pragma unroll
      for (int kh = 0; kh < 2; ++kh) {
        int row  = wm + mf * 16 + (lane & 15);
        int slot = (lane >> 4) + kh * 4;
        afr[mf][kh] = *reinterpret_cast<const short8*>(
            &As[buf][row * 64 + ((slot ^ (row & 7)) << 3)]);
      }
#pragma unroll
    for (int nf = 0; nf < NFC; ++nf)
#pragma unroll
      for (int kh = 0; kh < 2; ++kh) {
        int row  = wn + nf * 16 + (lane & 15);
        int slot = (lane >> 4) + kh * 4;
        bfr[nf][kh] = *reinterpret_cast<const short8*>(
            &Bs[buf][row * 64 + ((slot ^ (row & 7)) << 3)]);
      }
#pragma unroll
    for (int mf = 0; mf < 4; ++mf)
#pragma unroll
      for (int nf = 0; nf < NFC; ++nf)
#pragma unroll
        for (int kh = 0; kh < 2; ++kh)
          acc[mf][nf] = __builtin_amdgcn_mfma_f32_16x16x32_bf16(
              afr[mf][kh], bfr[nf][kh], acc[mf][nf], 0, 0, 0);
  }

#pragma unroll
  for (int mf = 0; mf < 4; ++mf)
#pragma unroll
    for (int nf = 0; nf < NFC; ++nf) {
      int mg = m0 + wm + mf * 16 + ((lane >> 4) << 2);
      int ng = n0 + wn + nf * 16 + (lane & 15);
      *reinterpret_cast<f32x4*>(&rawp[(size_t)ng * COUT + mg]) = acc[mf][nf];
    }
}

// ---------------------------------------------------------------------------
// LayerNorm + LeakyReLU + mask (sums NPART split-K partials). Wave per voxel.
// ---------------------------------------------------------------------------
template <int C, int NPART, bool BF16OUT>
__global__ __launch_bounds__(256) void ln_mask_k(
    const float* __restrict__ raw,
    const float* __restrict__ gamma,
    const float* __restrict__ beta,
    const uint8_t* __restrict__ msk,
    void* __restrict__ outv, int nvox)
{
  constexpr int E = C / 64;
  const int lane = threadIdx.x & 63;
  const int vox  = blockIdx.x * 4 + (threadIdx.x >> 6);
  if (vox >= nvox) return;

  const size_t stride = (size_t)nvox * C;
  const float* p = raw + (size_t)vox * C;
  float v[E];
  float s = 0.f, sq = 0.f;
#pragma unroll
  for (int e = 0; e < E; ++e) {
    float acc = 0.f;
#pragma unroll
    for (int pt = 0; pt < NPART; ++pt) acc += p[pt * stride + e * 64 + lane];
    v[e] = acc;
    s += acc; sq += acc * acc;
  }
#pragma unroll
  for (int off = 32; off; off >>= 1) {
    s  += __shfl_xor(s, off);
    sq += __shfl_xor(sq, off);
  }
  const float mean = s / (float)C;
  const float var  = sq / (float)C - mean * mean;
  const float rstd = rsqrtf(var + EPS);
  const float mk   = msk[vox] ? 1.f : 0.f;

#pragma unroll
  for (int e = 0; e < E; ++e) {
    int c = e * 64 + lane;
    float r = (v[e] - mean) * rstd * gamma[c] + beta[c];
    r = (r > 0.f ? r : SLOPE * r) * mk;
    if (BF16OUT)
      ((ushort*)outv)[(size_t)vox * C + c] = f2bf(r);
    else
      ((float*)outv)[(size_t)vox * C + c] = r;
  }
}

// ---------------------------------------------------------------------------
// Block4 LN + leaky + mask + per-group max + FUSED final max.
// ---------------------------------------------------------------------------
template <int NPART>
__global__ __launch_bounds__(256) void ln4max_k(
    const float* __restrict__ raw,      // [NPART][1024][512]
    const float* __restrict__ gamma,
    const float* __restrict__ beta,
    const uint8_t* __restrict__ msk,    // [1024]
    float* __restrict__ pm,             // [16][512]
    unsigned* __restrict__ cnt,         // zeroed each launch
    float* __restrict__ out)            // [2][512]
{
  const int t    = threadIdx.x;
  const int lane = t & 63;
  const int wave = t >> 6;
  const int grp  = blockIdx.x;          // 0..15
  const size_t stride = (size_t)1024 * 512;

  float gg[8], bb_[8];
#pragma unroll
  for (int e = 0; e < 8; ++e) {
    int c = e * 64 + lane;
    gg[e] = gamma[c]; bb_[e] = beta[c];
  }

  float vmax[8];
#pragma unroll
  for (int e = 0; e < 8; ++e) vmax[e] = -1e30f;

  for (int it = 0; it < 16; ++it) {
    const int vox = grp * 64 + wave * 16 + it;
    const float* p = raw + (size_t)vox * 512;
    float v[8];
    float s = 0.f, sq = 0.f;
#pragma unroll
    for (int e = 0; e < 8; ++e) {
      float a = 0.f;
#pragma unroll
      for (int pt = 0; pt < NPART; ++pt) a += p[pt * stride + e * 64 + lane];
      v[e] = a; s += a; sq += a * a;
    }
#pragma unroll
    for (int off = 32; off; off >>= 1) {
      s  += __shfl_xor(s, off);
      sq += __shfl_xor(sq, off);
    }
    const float mean = s * (1.f / 512.f);
    const float var  = sq * (1.f / 512.f) - mean * mean;
    const float rstd = rsqrtf(var + EPS);
    const float mk   = msk[vox] ? 1.f : 0.f;
#pragma unroll
    for (int e = 0; e < 8; ++e) {
      float r = (v[e] - mean) * rstd * gg[e] + bb_[e];
      r = (r > 0.f ? r : SLOPE * r) * mk;
      vmax[e] = fmaxf(vmax[e], r);
    }
  }

  __shared__ float red[4][512];
#pragma unroll
  for (int e = 0; e < 8; ++e) red[wave][e * 64 + lane] = vmax[e];
  __syncthreads();
  for (int c = t; c < 512; c += 256) {
    float m = fmaxf(fmaxf(red[0][c], red[1][c]), fmaxf(red[2][c], red[3][c]));
    pm[(size_t)grp * 512 + c] = m;
  }

  __threadfence();
  __shared__ unsigned isLast;
  if (t == 0) isLast = atomicAdd(cnt, 1u);
  __syncthreads();
  if (isLast == 15) {
    __threadfence();
    for (int i = t; i < 1024; i += 256) {      // i = b*512 + c
      int b = i >> 9, c = i & 511;
      float m = -1e30f;
#pragma unroll
      for (int g = 0; g < 8; ++g)
        m = fmaxf(m, pm[((size_t)b * 8 + g) * 512 + c]);
      out[i] = m;
    }
  }
}

// ---------------------------------------------------------------------------
extern "C" void kernel_launch(void* const* d_in, const int* in_sizes, int n_in,
                              void* d_out, int out_size, void* d_ws, size_t ws_size,
                              hipStream_t stream) {
  const float*   x    = (const float*)d_in[0];
  const uint8_t* mraw = (const uint8_t*)d_in[1];
  const float* w1 = (const float*)d_in[2];
  const float* g1 = (const float*)d_in[3];
  const float* b1 = (const float*)d_in[4];
  const float* w2 = (const float*)d_in[5];
  const float* g2 = (const float*)d_in[6];
  const float* b2 = (const float*)d_in[7];
  const float* w3 = (const float*)d_in[8];
  const float* g3 = (const float*)d_in[9];
  const float* b3 = (const float*)d_in[10];
  const float* w4 = (const float*)d_in[11];
  const float* g4 = (const float*)d_in[12];
  const float* b4 = (const float*)d_in[13];
  float* out = (float*)d_out;
  char*  ws  = (char*)d_ws;

  const size_t ZP   = 0;
  const size_t T1   = 256;
  const size_t R3b  = 67109120;
  const size_t T2   = 92274944;
  const size_t T3   = 109052160;
  const size_t PM   = 113246464;
  const size_t XCLP = 113279232;
  const size_t XCLP_BYTES = 4600064;
  const size_t WB1  = XCLP + XCLP_BYTES;
  const size_t WB2  = WB1 + 16384;
  const size_t WB3  = WB2 + 442368;
  const size_t WB4  = WB3 + 1769472;
  const size_t M1   = WB4 + 7077888;
  const size_t M2   = M1 + 524288;
  const size_t M3   = M2 + 65536;
  const size_t M4   = M3 + 8192;

  unsigned* flag = (unsigned*)(ws + ZP);
  unsigned* cnt  = (unsigned*)(ws + ZP + 4);
  const ushort* zpage = (const ushort*)(ws + ZP + 16);
  ushort* t1   = (ushort*)(ws + T1);
  float*  r3   = (float*)(ws + R3b);
  float*  r4   = (float*)(ws + R3b + 16777216);
  ushort* t2   = (ushort*)(ws + T2);
  ushort* t3   = (ushort*)(ws + T3);
  float*  pm   = (float*)(ws + PM);
  ushort* xclp = (ushort*)(ws + XCLP);
  ushort* wb1  = (ushort*)(ws + WB1);
  ushort* wb2  = (ushort*)(ws + WB2);
  ushort* wb3  = (ushort*)(ws + WB3);
  ushort* wb4  = (ushort*)(ws + WB4);
  uint8_t* m1  = (uint8_t*)(ws + M1);
  uint8_t* m2  = (uint8_t*)(ws + M2);
  uint8_t* m3  = (uint8_t*)(ws + M3);
  uint8_t* m4  = (uint8_t*)(ws + M4);

  const int NM1 = 2 * 64 * 64 * 64;

  hipMemsetAsync(ws + ZP, 0, 64, stream);
  zdetect_k<<<1124 + 256, 256, 0, stream>>>(
      (uint4*)(ws + XCLP), (int)(XCLP_BYTES / 16), mraw, NM1, flag);
  xclm_k<<<NM1 / 256, 256, 0, stream>>>(x, mraw, flag, m1, xclp);

  prep2_k<<<1189, 256, 0, stream>>>(w1, w2, w3, w4, wb1, wb2, wb3, wb4,
                                    m1, m2, m3, m4);

  conv1_gemm<<<512, 512, 0, stream>>>(xclp, wb1, g1, b1, m1, t1);

  conv2_gemm<<<512, 256, 0, stream>>>(t1, wb2, g2, b2, m2, t2, zpage);

  conv_gemm<128, 256, 32, 2, 7, 2, 64><<<dim3(128, 2, 2), 256, 0, stream>>>(
      t2, wb3, r3, zpage);
  ln_mask_k<256, 2, true><<<8192 / 4, 256, 0, stream>>>(r3, g3, b3, m3, t3, 8192);

  conv_gemm<256, 512, 16, 2, 8, 4, 64><<<dim3(16, 4, 4), 256, 0, stream>>>(
      t3, wb4, r4, zpage);
  ln4max_k<4><<<16, 256, 0, stream>>>(r4, g4, b4, m4, pm, cnt, out);

  (void)in_sizes; (void)n_in; (void)out_size; (void)ws_size;
}